// Round 13
// baseline (33.646 us; speedup 1.0000x reference)
//
#include <hip/hip_runtime.h>

#define H 4096
#define W 4096
#define R 8               // rows per SEGMENT (proven R7 geometry)
#define RB 16             // rows per BLOCK = 2 segments
#define TC 4              // cols per thread
#define TPB 256
#define STRIP (TPB*TC)    // 1024 cols per block
#define NSTRIP (W/STRIP)  // 4
#define NBAND (H/RB)      // 256 bands
#define NBLK (NSTRIP*NBAND) // 1024 blocks = 4/CU
#define BANDS_PER_XCD (NBAND/8) // 32
#define LN2 0.69314718055994531f

// R7's proven 8-row rolling-window segment, unchanged.
template<bool INTERIOR>
__device__ __forceinline__ float band_loss(const float* __restrict__ sp0,
                                           const float* __restrict__ op0,
                                           int r0, bool lv, bool rv) {
  float sa[TC], sb[TC], sc[TC];
  float oa[TC], ob[TC], oc[TC];
  float sLa, sLb, sLc, sRa, sRb, sRc;
  float oLa, oLb, oLc, oRa, oRb, oRc;

  const float* sp = sp0 - W;   // row r0-1
  const float* op = op0 - W;

  auto loadrow = [&](bool valid, float* sv, float* ov,
                     float& sl, float& sr, float& ol, float& orr) {
    if (valid) {
      const float4 fs = *reinterpret_cast<const float4*>(sp);
      const float4 fo = *reinterpret_cast<const float4*>(op);
      sv[0] = fs.x; sv[1] = fs.y; sv[2] = fs.z; sv[3] = fs.w;
      ov[0] = fo.x; ov[1] = fo.y; ov[2] = fo.z; ov[3] = fo.w;
      sl  = lv ? sp[-1] : 0.f;    // same vaddr, imm offset -4
      ol  = lv ? op[-1] : 0.f;
      sr  = rv ? sp[TC] : 0.f;    // imm offset +16
      orr = rv ? op[TC] : 0.f;
    } else {
      sv[0] = sv[1] = sv[2] = sv[3] = 0.f;
      ov[0] = ov[1] = ov[2] = ov[3] = 0.f;
      sl = sr = ol = orr = 0.f;
    }
  };

  loadrow(INTERIOR || (r0 - 1 >= 0), sa, oa, sLa, sRa, oLa, oRa);
  sp += W; op += W;
  loadrow(true, sb, ob, sLb, sRb, oLb, oRb);

  float acc = 0.f;

  #pragma unroll
  for (int i = 0; i < R; ++i) {
    sp += W; op += W;
    loadrow(INTERIOR || (r0 + i + 1 < H), sc, oc, sLc, sRc, oLc, oRc);

    float cs[TC], co[TC];
    #pragma unroll
    for (int k = 0; k < TC; ++k) {
      cs[k] = sa[k] + sb[k] + sc[k];
      co[k] = oa[k] + ob[k] + oc[k];
    }
    const float csL = sLa + sLb + sLc;
    const float csR = sRa + sRb + sRc;
    const float coL = oLa + oLb + oLc;
    const float coR = oRa + oRb + oRc;

    #pragma unroll
    for (int k = 0; k < TC; ++k) {
      const float cl  = (k == 0)    ? csL : cs[k-1];
      const float cr  = (k == TC-1) ? csR : cs[k+1];
      const float nsS = cl + cs[k] + cr - sb[k];     // 8-neighbor sum of seg
      const float col = (k == 0)    ? coL : co[k-1];
      const float cor = (k == TC-1) ? coR : co[k+1];
      const float nsO = col + co[k] + cor - ob[k];   // 8-neighbor sum of out
      const float w1 = 9.f - nsS;                    // sig_seg_1
      const float m0 = 1.f + nsO;                    // sig_out_0
      const float s = sb[k], o = ob[k];
      // log2 units; one LN2 scale at the very end (reduce kernel)
      acc += w1 * s * __log2f(o + 1e-5f) + m0 * (1.f - s) * __log2f(1.00001f - o);
    }

    #pragma unroll
    for (int k = 0; k < TC; ++k) {
      sa[k] = sb[k]; sb[k] = sc[k];
      oa[k] = ob[k]; ob[k] = oc[k];
    }
    sLa = sLb; sLb = sLc;  sRa = sRb; sRb = sRc;
    oLa = oLb; oLb = oLc;  oRa = oRb; oRb = oRc;
  }
  return acc;
}

__global__ __launch_bounds__(TPB)
void wbce_kernel(const float* __restrict__ outp, const float* __restrict__ segp,
                 float* __restrict__ partial) {
  // Bijective XCD swizzle (1024 % 8 == 0). Chunk = 128 blocks on one XCD;
  // within a chunk, consecutive blocks are consecutive 16-row bands of the
  // same strip -> band-boundary halo rows re-hit that XCD's L2.
  const int p     = blockIdx.x;
  const int xcd   = p & 7;
  const int idx   = p >> 3;                  // 0..127 within chunk
  const int strip = idx >> 5;                // 0..3 (32 bands per strip-run)
  const int band  = xcd * BANDS_PER_XCD + (idx & (BANDS_PER_XCD - 1));

  const int t     = threadIdx.x;
  const int r0    = band * RB;
  const int c0    = strip * STRIP + t * TC;
  const bool lv   = (c0 > 0);
  const bool rv   = (c0 + TC < W);

  const float* sp0 = segp + (size_t)r0 * W + c0;
  const float* op0 = outp + (size_t)r0 * W + c0;

  // Two sequential 8-row segments reusing the same window registers.
  // sched_barrier(0) at the seam stops the scheduler from hoisting segment-2
  // loads into segment 1 (R9's VGPR-176 failure mode). Seam rows r0+7, r0+8
  // are re-read by segment 2 from L1 (loaded ~us earlier by segment 1).
  float acc;
  if (band > 0) {
    acc = band_loss<true>(sp0, op0, r0, lv, rv);
    __builtin_amdgcn_sched_barrier(0);
    if (band < NBAND - 1)
      acc += band_loss<true >(sp0 + (size_t)R * W, op0 + (size_t)R * W, r0 + R, lv, rv);
    else
      acc += band_loss<false>(sp0 + (size_t)R * W, op0 + (size_t)R * W, r0 + R, lv, rv);
  } else {
    acc = band_loss<false>(sp0, op0, r0, lv, rv);
    __builtin_amdgcn_sched_barrier(0);
    acc += band_loss<true>(sp0 + (size_t)R * W, op0 + (size_t)R * W, r0 + R, lv, rv);
  }

  // wave reduce (64 lanes)
  #pragma unroll
  for (int off = 32; off > 0; off >>= 1) acc += __shfl_down(acc, off, 64);

  __shared__ float wsum[TPB / 64];
  if ((t & 63) == 0) wsum[t >> 6] = acc;
  __syncthreads();
  if (t == 0)
    partial[band * NSTRIP + strip] = wsum[0] + wsum[1] + wsum[2] + wsum[3];
}

__global__ __launch_bounds__(TPB)
void reduce_kernel(const float* __restrict__ partial, float* __restrict__ out) {
  const int t = threadIdx.x;
  const float4 v = reinterpret_cast<const float4*>(partial)[t];  // 1024 floats
  float a = v.x + v.y + v.z + v.w;
  #pragma unroll
  for (int off = 32; off > 0; off >>= 1) a += __shfl_down(a, off, 64);
  __shared__ float ws[TPB / 64];
  if ((t & 63) == 0) ws[t >> 6] = a;
  __syncthreads();
  if (t == 0)
    out[0] = (ws[0] + ws[1] + ws[2] + ws[3]) * (-LN2 / ((float)H * (float)W));
}

extern "C" void kernel_launch(void* const* d_in, const int* in_sizes, int n_in,
                              void* d_out, int out_size, void* d_ws, size_t ws_size,
                              hipStream_t stream) {
  const float* outp = (const float*)d_in[0];  // out_image
  const float* segp = (const float*)d_in[1];  // segment_image
  float* part = (float*)d_ws;                 // 1024 floats of scratch
  float* o = (float*)d_out;
  wbce_kernel<<<dim3(NBLK), TPB, 0, stream>>>(outp, segp, part);
  reduce_kernel<<<1, TPB, 0, stream>>>(part, o);
}